// Round 1
// baseline (8401.047 us; speedup 1.0000x reference)
//
#include <hip/hip_runtime.h>
#include <math.h>

namespace {

constexpr int Bn = 64, Ln = 256, Cn = 8, Dn = 512, Mn = 512;
constexpr int TWO_M = 2 * Mn;   // 1024
constexpr int BT = 4;           // batch rows per block
constexpr int MT = 32;          // m cols per block
constexpr int NMT = Mn / MT;    // 16
constexpr int PAD = 4;
constexpr int LDK = Dn + PAD;   // 516 (pad breaks power-of-2 bank aliasing)

// LDS carve (in floats)
constexpr int LDS_U16  = 4096;            // union: s_x (BT*LDK) / bpart(256*16) / fpart(32*32*4)
constexpr int LDS_CHS  = BT * LDK;        // 2064
constexpr int LDS_CH   = BT * Cn * LDK;   // 16512
constexpr int LDS_WFH  = MT * LDK;        // 16512
constexpr int LDS_CS   = BT * Cn * MT;    // 1024
constexpr int LDS_IOUF = 4 * BT * MT;     // 512
constexpr int LDS_FLOATS = LDS_U16 + LDS_CHS + LDS_CH + LDS_WFH + LDS_CS + LDS_IOUF + 32 + 4 + 32;
constexpr size_t LDS_BYTES = (size_t)LDS_FLOATS * 4;
static_assert(LDS_BYTES <= 163840, "over LDS budget");

__device__ __forceinline__ float sigmoidf_(float v) { return 1.0f / (1.0f + __expf(-v)); }

__global__ __launch_bounds__(256, 1)
void step_kernel(const float* __restrict__ x, const int* __restrict__ x_c,
                 const float* __restrict__ x_m, const float* __restrict__ x_m_c,
                 const float* __restrict__ W_ioux, const float* __restrict__ b_ioux,
                 const float* __restrict__ W_iouh, const float* __restrict__ b_iouh,
                 const float* __restrict__ W_fx, const float* __restrict__ b_fx,
                 const float* __restrict__ W_fh, const float* __restrict__ b_fh,
                 float* __restrict__ out, int t)
{
    extern __shared__ float lds[];
    float* u16    = lds;                    // scratch union
    float* s_chs  = u16 + LDS_U16;
    float* s_ch   = s_chs + LDS_CHS;
    float* s_wfh  = s_ch + LDS_CH;
    float* s_cs   = s_wfh + LDS_WFH;
    float* s_iouf = s_cs + LDS_CS;
    float* s_xmc  = s_iouf + LDS_IOUF;
    float* s_xm   = s_xmc + 32;
    int*   s_xc   = (int*)(s_xm + 4);

    const int tid = threadIdx.x;
    const int bx  = blockIdx.x;
    const int mt  = bx & (NMT - 1);   // m-tile varies fastest -> XCD-local weight slices
    const int bt  = bx >> 4;
    const int b0  = bt * BT;
    const int m0  = mt * MT;

    // ---------------- Phase A: load x rows, W_fh slice, scalars ----------------
    #pragma unroll
    for (int i = 0; i < 8; ++i) {
        int flat = i * 256 + tid;           // 0..2047
        int b = flat >> 9, k = flat & 511;
        u16[b * LDK + k] = x[((size_t)(b0 + b) * Ln + t) * Dn + k];
    }
    if (tid < 32) {
        int b = tid >> 3, c = tid & 7;
        s_xc[tid]  = x_c[((size_t)(b0 + b) * Ln + t) * Cn + c];
        s_xmc[tid] = x_m_c[((size_t)(b0 + b) * Ln + t) * Cn + c];
    }
    if (tid < 4) s_xm[tid] = x_m[(size_t)(b0 + tid) * Ln + t];
    for (int i = 0; i < 64; ++i) {
        int flat = i * 256 + tid;           // 0..16383
        int j = flat >> 9, k = flat & 511;
        s_wfh[j * LDK + k] = W_fh[(size_t)(m0 + j) * Dn + k];
    }
    __syncthreads();

    // ---------------- Phase A2: gather children (predicated idx < t) ----------------
    #pragma unroll
    for (int i = 0; i < 8; ++i) {
        int flat = i * 256 + tid;
        int b = flat >> 9, k = flat & 511;
        float acc = 0.f;
        #pragma unroll
        for (int c = 0; c < Cn; ++c) {
            int idx = s_xc[b * 8 + c];
            float v = 0.f;
            if (idx < t) v = out[((size_t)(b0 + b) * Ln + idx) * TWO_M + Mn + k];
            s_ch[(b * 8 + c) * LDK + k] = v;
            acc += s_xmc[b * 8 + c] * v;
        }
        s_chs[b * LDK + k] = acc;
    }
    #pragma unroll
    for (int i = 0; i < 4; ++i) {
        int flat = i * 256 + tid;           // 0..1023
        int b = flat >> 8, rem = flat & 255, c = rem >> 5, j = rem & 31;
        int idx = s_xc[b * 8 + c];
        float v = 0.f;
        if (idx < t) v = out[((size_t)(b0 + b) * Ln + idx) * TWO_M + m0 + j];
        s_cs[flat] = v;
    }
    __syncthreads();

    // ---------------- Phase B: iou (i,o,u strips) + fx dots ----------------
    {
        const int unit = tid >> 3;          // 0..31
        const int ks   = tid & 7;           // 0..7 (k-interleaved -> all 32 banks, 128B gmem segs)
        const int s    = unit >> 3;         // 0..3 wave-uniform strip
        const int jg   = unit & 7;
        float acc[4][4];
        #pragma unroll
        for (int b = 0; b < 4; ++b)
            #pragma unroll
            for (int jj = 0; jj < 4; ++jj) acc[b][jj] = 0.f;

        if (s < 3) {
            const int colbase = s * Mn + m0 + jg * 4;
            #pragma unroll 4
            for (int it = 0; it < 16; ++it) {
                const int k = it * 32 + ks * 4;
                float4 sx[4], sc[4];
                #pragma unroll
                for (int b = 0; b < 4; ++b) {
                    sx[b] = *(const float4*)&u16[b * LDK + k];
                    sc[b] = *(const float4*)&s_chs[b * LDK + k];
                }
                #pragma unroll
                for (int jj = 0; jj < 4; ++jj) {
                    const float4 wx = *(const float4*)&W_ioux[(size_t)(colbase + jj) * Dn + k];
                    const float4 wh = *(const float4*)&W_iouh[(size_t)(colbase + jj) * Dn + k];
                    #pragma unroll
                    for (int b = 0; b < 4; ++b) {
                        acc[b][jj] += sx[b].x * wx.x + sx[b].y * wx.y + sx[b].z * wx.z + sx[b].w * wx.w
                                    + sc[b].x * wh.x + sc[b].y * wh.y + sc[b].z * wh.z + sc[b].w * wh.w;
                    }
                }
            }
        } else {
            const int colbase = m0 + jg * 4;
            #pragma unroll 4
            for (int it = 0; it < 16; ++it) {
                const int k = it * 32 + ks * 4;
                float4 sx[4];
                #pragma unroll
                for (int b = 0; b < 4; ++b) sx[b] = *(const float4*)&u16[b * LDK + k];
                #pragma unroll
                for (int jj = 0; jj < 4; ++jj) {
                    const float4 wx = *(const float4*)&W_fx[(size_t)(colbase + jj) * Dn + k];
                    #pragma unroll
                    for (int b = 0; b < 4; ++b)
                        acc[b][jj] += sx[b].x * wx.x + sx[b].y * wx.y + sx[b].z * wx.z + sx[b].w * wx.w;
                }
            }
        }
        __syncthreads();   // done reading s_x region of u16
        #pragma unroll
        for (int b = 0; b < 4; ++b)
            #pragma unroll
            for (int jj = 0; jj < 4; ++jj)
                u16[unit * 128 + ks * 16 + b * 4 + jj] = acc[b][jj];
        __syncthreads();
        #pragma unroll
        for (int e = 0; e < 2; ++e) {
            const int task = e * 256 + tid;     // 0..511
            const int unit2 = task >> 4;
            const int rem   = task & 15;
            float v = 0.f;
            #pragma unroll
            for (int k2 = 0; k2 < 8; ++k2) v += u16[unit2 * 128 + k2 * 16 + rem];
            const int s2 = unit2 >> 3, jg2 = unit2 & 7;
            const int bb = rem >> 2, jj = rem & 3;
            const int j  = jg2 * 4 + jj;
            float bias;
            if (s2 < 3) bias = b_ioux[s2 * Mn + m0 + j] + b_iouh[s2 * Mn + m0 + j];
            else        bias = b_fx[m0 + j];
            s_iouf[(s2 * 4 + bb) * 32 + j] = v + bias;
        }
    }
    __syncthreads();

    // ---------------- Phase C: f-matmul (32 gathered rows x 32 cols x 512) ----------------
    {
        const int pos = tid >> 2, ksc = tid & 3;
        const int rg = pos >> 3, jg = pos & 7;
        float acc[4][4];
        #pragma unroll
        for (int r = 0; r < 4; ++r)
            #pragma unroll
            for (int j = 0; j < 4; ++j) acc[r][j] = 0.f;
        #pragma unroll 4
        for (int it = 0; it < 32; ++it) {
            const int k = it * 16 + ksc * 4;
            float4 ch[4], wf[4];
            #pragma unroll
            for (int r = 0; r < 4; ++r) ch[r] = *(const float4*)&s_ch[(rg * 4 + r) * LDK + k];
            #pragma unroll
            for (int j = 0; j < 4; ++j) wf[j] = *(const float4*)&s_wfh[(jg * 4 + j) * LDK + k];
            #pragma unroll
            for (int r = 0; r < 4; ++r)
                #pragma unroll
                for (int j = 0; j < 4; ++j)
                    acc[r][j] += ch[r].x * wf[j].x + ch[r].y * wf[j].y + ch[r].z * wf[j].z + ch[r].w * wf[j].w;
        }
        // u16 free since last barrier: write f partials [row][col][ks]
        #pragma unroll
        for (int r = 0; r < 4; ++r)
            #pragma unroll
            for (int j = 0; j < 4; ++j)
                u16[((rg * 4 + r) * 32 + (jg * 4 + j)) * 4 + ksc] = acc[r][j];
    }
    __syncthreads();

    // ---------------- Phase D: gates, c/h, mask-blend, store ----------------
    if (tid < 128) {
        const int b = tid >> 5, j = tid & 31;
        const float iv  = s_iouf[(0 * 4 + b) * 32 + j];
        const float ov  = s_iouf[(1 * 4 + b) * 32 + j];
        const float uv  = s_iouf[(2 * 4 + b) * 32 + j];
        const float fxv = s_iouf[(3 * 4 + b) * 32 + j];
        const float i_ = sigmoidf_(iv);
        const float o_ = sigmoidf_(ov);
        const float u_ = tanhf(uv);
        const float bfh = b_fh[m0 + j];
        float facc = 0.f;
        #pragma unroll
        for (int c = 0; c < Cn; ++c) {
            const int row = b * 8 + c;
            const float fd = u16[(row * 32 + j) * 4 + 0] + u16[(row * 32 + j) * 4 + 1]
                           + u16[(row * 32 + j) * 4 + 2] + u16[(row * 32 + j) * 4 + 3];
            const float f = sigmoidf_(fd + bfh + fxv);
            facc += f * s_cs[row * 32 + j] * s_xmc[row];
        }
        const float cval = i_ * u_ + facc;
        const float hval = o_ * tanhf(cval);
        const float mval = s_xm[b];
        const size_t base  = ((size_t)(b0 + b) * Ln + t) * TWO_M;
        const size_t pbase = ((size_t)(b0 + b) * Ln + (t - 1)) * TWO_M;
        const float pc = out[pbase + m0 + j];
        const float ph = out[pbase + Mn + m0 + j];
        out[base + m0 + j]      = mval * cval + (1.f - mval) * pc;
        out[base + Mn + m0 + j] = mval * hval + (1.f - mval) * ph;
    }
}

__global__ void zero_row0(float* __restrict__ out) {
    int i = blockIdx.x * 256 + threadIdx.x;      // 65536 total
    int b = i >> 10, j = i & 1023;
    out[(size_t)b * Ln * TWO_M + j] = 0.f;
}

__global__ void final_copy(const float* __restrict__ out, float* __restrict__ fin) {
    int i = blockIdx.x * 256 + threadIdx.x;      // 65536 total
    int b = i >> 10, j = i & 1023;
    fin[i] = out[((size_t)b * Ln + (Ln - 1)) * TWO_M + j];
}

} // namespace

extern "C" void kernel_launch(void* const* d_in, const int* in_sizes, int n_in,
                              void* d_out, int out_size, void* d_ws, size_t ws_size,
                              hipStream_t stream) {
    (void)in_sizes; (void)n_in; (void)d_ws; (void)ws_size; (void)out_size;
    const float* x      = (const float*)d_in[0];
    const int*   x_c    = (const int*)d_in[1];
    const float* x_m    = (const float*)d_in[2];
    const float* x_m_c  = (const float*)d_in[3];
    const float* W_ioux = (const float*)d_in[4];
    const float* b_ioux = (const float*)d_in[5];
    const float* W_iouh = (const float*)d_in[6];
    const float* b_iouh = (const float*)d_in[7];
    const float* W_fx   = (const float*)d_in[8];
    const float* b_fx   = (const float*)d_in[9];
    const float* W_fh   = (const float*)d_in[10];
    const float* b_fh   = (const float*)d_in[11];
    float* out = (float*)d_out;
    float* fin = out + (size_t)Bn * Ln * TWO_M;

    static bool attr_set = false;
    if (!attr_set) {
        hipFuncSetAttribute((const void*)step_kernel,
                            hipFuncAttributeMaxDynamicSharedMemorySize,
                            (int)LDS_BYTES);
        attr_set = true;
    }

    hipLaunchKernelGGL(zero_row0, dim3(256), dim3(256), 0, stream, out);
    for (int t = 1; t < Ln; ++t) {
        hipLaunchKernelGGL(step_kernel, dim3(256), dim3(256), LDS_BYTES, stream,
                           x, x_c, x_m, x_m_c, W_ioux, b_ioux, W_iouh, b_iouh,
                           W_fx, b_fx, W_fh, b_fh, out, t);
    }
    hipLaunchKernelGGL(final_copy, dim3(256), dim3(256), 0, stream, out, fin);
}